// Round 2
// baseline (1061.141 us; speedup 1.0000x reference)
//
#include <hip/hip_runtime.h>
#include <hip/hip_bf16.h>

typedef unsigned short ushort;
typedef __attribute__((ext_vector_type(4))) float floatx4;
typedef __attribute__((ext_vector_type(8))) short short8;

constexpr int NB   = 512;
constexpr int T    = 43;
constexpr int H    = 128;
constexpr int NT   = NB * T;       // 22016
constexpr int DK   = 96;
constexpr int DFF  = 2048;
constexpr int OUTD = 8000;

__device__ __forceinline__ ushort f2b(float f) {
    __hip_bfloat16 h = __float2bfloat16(f);
    return *reinterpret_cast<ushort*>(&h);
}

#define GLOAD16(g, l) __builtin_amdgcn_global_load_lds( \
    (const __attribute__((address_space(1))) unsigned int*)(g), \
    (__attribute__((address_space(3))) unsigned int*)(l), 16, 0, 0)

// ---------------------------------------------------------------------------
// GEMM: C[M,N] = A[M,K](bf16) @ B[Npad,K](bf16)^T + bias ; optional relu/bf16
// 128x128 tile, BK=32, 4 waves, 4x4 16x16x32 MFMA frags per wave.
// M % 128 == 0, K % 32 == 0, Npad % 128 == 0 (B zero-padded), store guard col<N
// ---------------------------------------------------------------------------
template<bool RELU, bool OUT_BF16>
__global__ __launch_bounds__(256) void gemm_bt(
    const ushort* __restrict__ A, const ushort* __restrict__ B,
    const float* __restrict__ bias, void* __restrict__ Cv,
    int M, int N, int K)
{
    __shared__ ushort As[128 * 32];
    __shared__ ushort Bs[128 * 32];
    const int tid  = threadIdx.x;
    const int lane = tid & 63;
    const int wm   = (tid >> 6) & 1;
    const int wn   = (tid >> 6) >> 1;
    const long tileM = (long)blockIdx.y * 128;
    const long tileN = (long)blockIdx.x * 128;

    floatx4 acc[4][4] = {};

    // staging: 512 chunks of 16B per tile; chunk c -> row c>>2, k-off (c&3)*8
    const ushort* ga0 = A + (tileM + (tid >> 2)) * (long)K + (tid & 3) * 8;
    const ushort* ga1 = A + (tileM + 64 + (tid >> 2)) * (long)K + (tid & 3) * 8;
    const ushort* gb0 = B + (tileN + (tid >> 2)) * (long)K + (tid & 3) * 8;
    const ushort* gb1 = B + (tileN + 64 + (tid >> 2)) * (long)K + (tid & 3) * 8;
    ushort* la0 = &As[tid * 8];
    ushort* la1 = &As[(tid + 256) * 8];
    ushort* lb0 = &Bs[tid * 8];
    ushort* lb1 = &Bs[(tid + 256) * 8];

    for (int k0 = 0; k0 < K; k0 += 32) {
        __syncthreads();
        GLOAD16(ga0 + k0, la0);
        GLOAD16(ga1 + k0, la1);
        GLOAD16(gb0 + k0, lb0);
        GLOAD16(gb1 + k0, lb1);
        __syncthreads();
        short8 af[4], bfr[4];
        #pragma unroll
        for (int mi = 0; mi < 4; ++mi)
            af[mi] = *(const short8*)&As[(wm * 64 + mi * 16 + (lane & 15)) * 32 + (lane >> 4) * 8];
        #pragma unroll
        for (int ni = 0; ni < 4; ++ni)
            bfr[ni] = *(const short8*)&Bs[(wn * 64 + ni * 16 + (lane & 15)) * 32 + (lane >> 4) * 8];
        #pragma unroll
        for (int mi = 0; mi < 4; ++mi)
            #pragma unroll
            for (int ni = 0; ni < 4; ++ni)
                acc[mi][ni] = __builtin_amdgcn_mfma_f32_16x16x32_bf16(
                    af[mi], bfr[ni], acc[mi][ni], 0, 0, 0);
    }

    const int r0 = wm * 64 + (lane >> 4) * 4;
    const int c0 = wn * 64 + (lane & 15);
    #pragma unroll
    for (int ni = 0; ni < 4; ++ni) {
        long col = tileN + c0 + ni * 16;
        if (col < N) {
            float bv = bias ? bias[col] : 0.0f;
            #pragma unroll
            for (int mi = 0; mi < 4; ++mi) {
                #pragma unroll
                for (int r = 0; r < 4; ++r) {
                    long row = tileM + r0 + mi * 16 + r;
                    float v = acc[mi][ni][r] + bv;
                    if (RELU) v = v > 0.0f ? v : 0.0f;
                    if (OUT_BF16) ((ushort*)Cv)[row * N + col] = f2b(v);
                    else          ((float*)Cv)[row * N + col] = v;
                }
            }
        }
    }
}

// ---------------------------------------------------------------------------
// embed: x = emb[inputs] + pos_emb  (fp32 + bf16 copies)
// ---------------------------------------------------------------------------
__global__ __launch_bounds__(256) void embed_kernel(
    const int* __restrict__ inputs, const float* __restrict__ emb,
    const float* __restrict__ pos, float* __restrict__ xf, ushort* __restrict__ xb)
{
    long i = (long)blockIdx.x * 256 + threadIdx.x;   // over NT*H
    int h  = (int)(i & 127);
    int nt = (int)(i >> 7);
    int t  = nt % T;
    float v = emb[(long)inputs[nt] * H + h] + pos[t * H + h];
    xf[i] = v;
    xb[i] = f2b(v);
}

// ---------------------------------------------------------------------------
// pack 6 qkv weights [96,128] -> [640,128] bf16 (zero pad), biases -> [640]
// order: q1,k1,v1,q2,k2,v2
// ---------------------------------------------------------------------------
__global__ __launch_bounds__(256) void pack_qkv(
    const float* q1, const float* k1, const float* v1,
    const float* q2, const float* k2, const float* v2,
    const float* bq1, const float* bk1, const float* bv1,
    const float* bq2, const float* bk2, const float* bv2,
    ushort* __restrict__ W, float* __restrict__ bias)
{
    int i = blockIdx.x * 256 + threadIdx.x;   // 640*128
    int n = i >> 7, kk = i & 127;
    float val = 0.0f;
    if (n < 576) {
        const float* ws[6] = {q1, k1, v1, q2, k2, v2};
        val = ws[n / 96][(n % 96) * 128 + kk];
    }
    W[i] = f2b(val);
    if (kk == 0) {
        float bv = 0.0f;
        if (n < 576) {
            const float* bs[6] = {bq1, bk1, bv1, bq2, bk2, bv2};
            bv = bs[n / 96][n % 96];
        }
        bias[n] = bv;
    }
}

// ---------------------------------------------------------------------------
// fp32 -> bf16 weight convert with optional row padding
// ---------------------------------------------------------------------------
__global__ __launch_bounds__(256) void cvt_w(
    const float* __restrict__ src, ushort* __restrict__ dst,
    int rows, int cols, int rows_pad)
{
    long i = (long)blockIdx.x * 256 + threadIdx.x;
    if (i >= (long)rows_pad * cols) return;
    long r = i / cols;
    dst[i] = f2b(r < rows ? src[i] : 0.0f);
}

// ---------------------------------------------------------------------------
// attention: one block per (head, batch). qkv fp32 [NT,576] layout
// [q1 k1 v1 q2 k2 v2] (96 each). writes h12 bf16 [NT,192].
// ---------------------------------------------------------------------------
__global__ __launch_bounds__(256) void attn_kernel(
    const float* __restrict__ qkv, ushort* __restrict__ h12)
{
    const int head = blockIdx.x;
    const int n    = blockIdx.y;
    const int tid  = threadIdx.x;
    __shared__ float q[T][DK], k[T][DK], v[T][DK];
    __shared__ float s[T][T + 1];
    const float scale = 0.10206207261596575f;   // 1/sqrt(96)
    const long base = (long)n * T * 576 + head * 288;

    for (int i = tid; i < T * DK; i += 256) {
        int r = i / DK, c = i % DK;
        q[r][c] = qkv[base + r * 576 + c];
        k[r][c] = qkv[base + r * 576 + 96 + c];
        v[r][c] = qkv[base + r * 576 + 192 + c];
    }
    __syncthreads();
    for (int i = tid; i < T * T; i += 256) {
        int r = i / T, c = i % T;
        float d = 0.0f;
        #pragma unroll 8
        for (int x = 0; x < DK; ++x) d += q[r][x] * k[c][x];
        s[r][c] = d * scale;
    }
    __syncthreads();
    if (tid < T) {
        float mx = -1e30f;
        for (int j = 0; j < T; ++j) mx = fmaxf(mx, s[tid][j]);
        float sum = 0.0f;
        for (int j = 0; j < T; ++j) { float e = __expf(s[tid][j] - mx); s[tid][j] = e; sum += e; }
        float inv = 1.0f / sum;
        for (int j = 0; j < T; ++j) s[tid][j] *= inv;
    }
    __syncthreads();
    for (int i = tid; i < T * DK; i += 256) {
        int r = i / DK, c = i % DK;
        float d = 0.0f;
        #pragma unroll
        for (int j = 0; j < T; ++j) d += s[r][j] * v[j][c];
        h12[((long)n * T + r) * 192 + head * 96 + c] = f2b(d);
    }
}

// ---------------------------------------------------------------------------
// residual + LayerNorm, wave per row (H=128, 2 elems/lane)
// ---------------------------------------------------------------------------
__global__ __launch_bounds__(256) void ln_kernel(
    const float* __restrict__ a, const float* __restrict__ resid,
    const float* __restrict__ g, const float* __restrict__ b,
    ushort* __restrict__ out_bf, float* __restrict__ out_f32, int M)
{
    const int lane = threadIdx.x & 63;
    const int row  = blockIdx.x * 4 + (threadIdx.x >> 6);
    if (row >= M) return;
    const long o = (long)row * H;
    float v0 = a[o + lane] + resid[o + lane];
    float v1 = a[o + 64 + lane] + resid[o + 64 + lane];
    float s  = v0 + v1, sq = v0 * v0 + v1 * v1;
    #pragma unroll
    for (int w = 32; w; w >>= 1) { s += __shfl_xor(s, w, 64); sq += __shfl_xor(sq, w, 64); }
    float mean = s * (1.0f / H);
    float var  = sq * (1.0f / H) - mean * mean;
    float rstd = rsqrtf(var + 1e-5f);
    float o0 = (v0 - mean) * rstd * g[lane] + b[lane];
    float o1 = (v1 - mean) * rstd * g[64 + lane] + b[64 + lane];
    out_bf[o + lane] = f2b(o0);
    out_bf[o + 64 + lane] = f2b(o1);
    if (out_f32) { out_f32[o + lane] = o0; out_f32[o + 64 + lane] = o1; }
}

// ---------------------------------------------------------------------------
extern "C" void kernel_launch(void* const* d_in, const int* in_sizes, int n_in,
                              void* d_out, int out_size, void* d_ws, size_t ws_size,
                              hipStream_t stream)
{
    const int*   inputs  = (const int*)  d_in[0];
    const float* emb     = (const float*)d_in[1];
    const float* pos_emb = (const float*)d_in[2];
    const float* Wk1 = (const float*)d_in[3],  *bk1 = (const float*)d_in[4];
    const float* Wv1 = (const float*)d_in[5],  *bv1 = (const float*)d_in[6];
    const float* Wq1 = (const float*)d_in[7],  *bq1 = (const float*)d_in[8];
    const float* Wk2 = (const float*)d_in[9],  *bk2 = (const float*)d_in[10];
    const float* Wv2 = (const float*)d_in[11], *bv2 = (const float*)d_in[12];
    const float* Wq2 = (const float*)d_in[13], *bq2 = (const float*)d_in[14];
    const float* Wproj = (const float*)d_in[15], *bproj = (const float*)d_in[16];
    const float* g_mh  = (const float*)d_in[17], *b_mh  = (const float*)d_in[18];
    const float* Wff1  = (const float*)d_in[19], *bff1  = (const float*)d_in[20];
    const float* Wff2  = (const float*)d_in[21], *bff2  = (const float*)d_in[22];
    const float* g_ff  = (const float*)d_in[23], *b_ff  = (const float*)d_in[24];
    const float* Wfin  = (const float*)d_in[25], *bfin  = (const float*)d_in[26];

    // --- Scratch placement ---------------------------------------------------
    // d_out is NT*8000 fp32 = 704.5 MB, written in full by the FINAL gemm only.
    // Everything dead before the final gemm lives in d_out-as-scratch.
    // Only buffers read DURING the final gemm (y_b, Wf_b) live in d_ws
    // (~7.7 MB total) — previous round's 215 MB ws usage overflowed ws_size
    // and corrupted the harness's pristine input copies.
    char* scr = (char*)d_out;
    size_t soff = 0;
    auto salloc = [&](size_t bytes) {
        void* p = scr + soff;
        soff = (soff + bytes + 255) & ~(size_t)255;
        return p;
    };
    float*  x_f   = (float*) salloc((size_t)NT * H * 4);
    ushort* x_b   = (ushort*)salloc((size_t)NT * H * 2);
    float*  qkv   = (float*) salloc((size_t)NT * 576 * 4);
    ushort* h12   = (ushort*)salloc((size_t)NT * 192 * 2);
    float*  mh    = (float*) salloc((size_t)NT * H * 4);
    float*  xln_f = (float*) salloc((size_t)NT * H * 4);
    ushort* xln_b = (ushort*)salloc((size_t)NT * H * 2);
    ushort* ffa   = (ushort*)salloc((size_t)NT * DFF * 2);
    float*  ff2   = (float*) salloc((size_t)NT * H * 4);
    ushort* Wqkv  = (ushort*)salloc(640 * 128 * 2);
    float*  bqkv  = (float*) salloc(640 * 4);
    ushort* Wp_b  = (ushort*)salloc(128 * 192 * 2);
    ushort* W1_b  = (ushort*)salloc((size_t)DFF * 128 * 2);
    ushort* W2_b  = (ushort*)salloc((size_t)128 * DFF * 2);
    // total scratch-in-d_out ~207 MB << 704 MB

    char* ws = (char*)d_ws;
    size_t woff = 0;
    auto walloc = [&](size_t bytes) {
        void* p = ws + woff;
        woff = (woff + bytes + 255) & ~(size_t)255;
        return p;
    };
    ushort* y_b  = (ushort*)walloc((size_t)NT * H * 2);      // 5.6 MB
    ushort* Wf_b = (ushort*)walloc((size_t)8064 * 128 * 2);  // 2.1 MB

    // weight conversion / packing
    pack_qkv<<<(640 * 128) / 256, 256, 0, stream>>>(
        Wq1, Wk1, Wv1, Wq2, Wk2, Wv2, bq1, bk1, bv1, bq2, bk2, bv2, Wqkv, bqkv);
    cvt_w<<<(128 * 192) / 256, 256, 0, stream>>>(Wproj, Wp_b, 128, 192, 128);
    cvt_w<<<(DFF * 128) / 256, 256, 0, stream>>>(Wff1, W1_b, DFF, 128, DFF);
    cvt_w<<<(128 * DFF) / 256, 256, 0, stream>>>(Wff2, W2_b, 128, DFF, 128);
    cvt_w<<<(8064 * 128) / 256, 256, 0, stream>>>(Wfin, Wf_b, OUTD, 128, 8064);

    // embed
    embed_kernel<<<(NT * H) / 256, 256, 0, stream>>>(inputs, emb, pos_emb, x_f, x_b);

    const int MT = NT / 128;   // 172 M-tiles

    // QKV projection: [NT,128] @ [640,128]^T -> [NT,576] fp32
    gemm_bt<false, false><<<dim3(5, MT), 256, 0, stream>>>(x_b, Wqkv, bqkv, qkv, NT, 576, 128);

    // attention -> h12 bf16 [NT,192]
    attn_kernel<<<dim3(2, NB), 256, 0, stream>>>(qkv, h12);

    // Wproj: [NT,192] @ [128,192]^T -> mh fp32 [NT,128]
    gemm_bt<false, false><<<dim3(1, MT), 256, 0, stream>>>(h12, Wp_b, bproj, mh, NT, 128, 192);

    // LN1: xln = LN(mh + x)
    ln_kernel<<<NT / 4, 256, 0, stream>>>(mh, x_f, g_mh, b_mh, xln_b, xln_f, NT);

    // FFN1 + relu -> bf16 [NT,2048]
    gemm_bt<true, true><<<dim3(DFF / 128, MT), 256, 0, stream>>>(xln_b, W1_b, bff1, ffa, NT, DFF, 128);

    // FFN2 -> fp32 [NT,128]
    gemm_bt<false, false><<<dim3(1, MT), 256, 0, stream>>>(ffa, W2_b, bff2, ff2, NT, 128, DFF);

    // LN2: y = LN(ff2 + xln)
    ln_kernel<<<NT / 4, 256, 0, stream>>>(ff2, xln_f, g_ff, b_ff, y_b, nullptr, NT);

    // final: [NT,128] @ [8064,128]^T -> d_out fp32 [NT,8000]
    gemm_bt<false, false><<<dim3(63, MT), 256, 0, stream>>>(y_b, Wf_b, bfin, (float*)d_out, NT, OUTD, 128);
}